// Round 4
// baseline (979.068 us; speedup 1.0000x reference)
//
#include <hip/hip_runtime.h>
#include <cstdint>
#include <cstddef>

typedef unsigned short u16;
typedef __bf16 bf16x8 __attribute__((ext_vector_type(8)));
typedef float f32x4 __attribute__((ext_vector_type(4)));

#define MAXDISP 48
#define HH 64
#define WW 128

// ---------- bf16 helpers ----------
__device__ __forceinline__ float bf2f(unsigned int x) {
    union { unsigned int i; float f; } c; c.i = x << 16; return c.f;
}
__device__ __forceinline__ float bf2f_hi(unsigned int x) {
    union { unsigned int i; float f; } c; c.i = x & 0xffff0000u; return c.f;
}
__device__ __forceinline__ u16 f2bf(float f) {
    union { float f; unsigned int i; } c; c.f = f;
    unsigned int x = c.i;
    return (u16)((x + 0x7fffu + ((x >> 16) & 1u)) >> 16);   // RNE
}

// ---------- weight transform: BN-fold + swizzle into MFMA B-fragment order ----------
// dst[tap][nt][kc][lane][j] bf16, tap=kd*3+kh, co=nt*16+(lane&15),
// k-chunk kc: CIN=64: kw=kc>>1, c=(kc&1)*32+(lane>>4)*8+j ; CIN=32: kw=kc, c=(lane>>4)*8+j
__global__ __launch_bounds__(256) void wfrag_kernel(
    const float* __restrict__ w, const float* __restrict__ gam,
    const float* __restrict__ bet, const float* __restrict__ mea,
    const float* __restrict__ var,
    u16* __restrict__ dst, float* __restrict__ bias, int CIN, int KC)
{
    int idx = blockIdx.x * 256 + threadIdx.x;
    int n = 9 * 2 * KC * 512;
    if (idx < n) {
        int j    = idx & 7;
        int lane = (idx >> 3) & 63;
        int t2   = idx >> 9;
        int kc   = t2 % KC;
        int t3   = t2 / KC;
        int nt   = t3 & 1;
        int tap  = t3 >> 1;
        int co   = nt * 16 + (lane & 15);
        int qq   = lane >> 4;
        int kw, c;
        if (CIN == 64) { kw = kc >> 1; c = (kc & 1) * 32 + qq * 8 + j; }
        else           { kw = kc;      c = qq * 8 + j; }
        int kd = tap / 3, kh = tap % 3;
        float inv = gam[co] * rsqrtf(var[co] + 1e-5f);
        dst[idx] = f2bf(w[((size_t)co * CIN + c) * 27 + kd * 9 + kh * 3 + kw] * inv);
    }
    if (blockIdx.x == 0 && threadIdx.x < 32) {
        int co = threadIdx.x;
        float inv = gam[co] * rsqrtf(var[co] + 1e-5f);
        bias[co] = bet[co] - mea[co] * inv;
    }
}

// ---------- cost volume, channel-last: vol[bl][d][h][w][c64] bf16 ----------
// block = (bl, dquarter, h); rg+rc staged transposed [w][c] bf16 in LDS; corr
// computed from fp32 lg (registers) x bf16 rg (LDS); out slab per 4 d.
#define RS 334   // r_s row stride (u16): stride/2 odd -> 2-way-free b32 reads
__global__ __launch_bounds__(256) void vol_build_kernel(
    const float* __restrict__ lg, const float* __restrict__ rg,
    const float* __restrict__ lc, const float* __restrict__ rc,
    u16* __restrict__ vol, int b0)
{
    __shared__ u16 r_s[128 * RS];       // [w][0..319 rg | 320..331 rc]
    __shared__ u16 o_s[4 * 128 * 68];   // [dl][w][c64 +4 pad]

    int bi  = blockIdx.x;               // bl*256 + dq*64 + h
    int h   = bi & 63;
    int dq  = (bi >> 6) & 3;
    int bl  = bi >> 8;
    int b   = b0 + bl;
    int tid = threadIdx.x;
    int w    = tid & 127;
    int part = tid >> 7;

    for (int idx = tid; idx < 320 * 32; idx += 256) {
        int c = idx >> 5, w4 = (idx & 31) << 2;
        const float4 v = *(const float4*)(rg + (((size_t)b * 320 + c) * 64 + h) * 128 + w4);
        r_s[(w4 + 0) * RS + c] = f2bf(v.x);
        r_s[(w4 + 1) * RS + c] = f2bf(v.y);
        r_s[(w4 + 2) * RS + c] = f2bf(v.z);
        r_s[(w4 + 3) * RS + c] = f2bf(v.w);
    }
    for (int idx = tid; idx < 12 * 32; idx += 256) {
        int c = idx >> 5, w4 = (idx & 31) << 2;
        const float4 v = *(const float4*)(rc + (((size_t)b * 12 + c) * 64 + h) * 128 + w4);
        r_s[(w4 + 0) * RS + 320 + c] = f2bf(v.x);
        r_s[(w4 + 1) * RS + 320 + c] = f2bf(v.y);
        r_s[(w4 + 2) * RS + 320 + c] = f2bf(v.z);
        r_s[(w4 + 3) * RS + 320 + c] = f2bf(v.w);
    }
    u16 lcv[12];
    if (part == 0) {
#pragma unroll
        for (int k = 0; k < 12; k++)
            lcv[k] = f2bf(lc[(((size_t)b * 12 + k) * 64 + h) * 128 + w]);
    }
    __syncthreads();

    int d0 = dq * 12;
    for (int dc = 0; dc < 12; dc += 4) {
        // ---- corr channels: part0 g 0..19, part1 g 20..39 ----
        for (int gb = 0; gb < 5; gb++) {
            int g0 = part * 20 + gb * 4;
            float lv[4][8];
#pragma unroll
            for (int gg = 0; gg < 4; gg++)
#pragma unroll
                for (int j = 0; j < 8; j++)
                    lv[gg][j] = lg[(((size_t)b * 320 + (g0 + gg) * 8 + j) * 64 + h) * 128 + w];
#pragma unroll
            for (int dl = 0; dl < 4; dl++) {
                int d = d0 + dc + dl;
                union { u16 us[4]; uint2 u2; } pk;
                pk.us[0] = pk.us[1] = pk.us[2] = pk.us[3] = 0;
                if (w >= d) {
#pragma unroll
                    for (int gg = 0; gg < 4; gg++) {
                        float s = 0.f;
                        int base = (w - d) * RS + (g0 + gg) * 8;
#pragma unroll
                        for (int jj = 0; jj < 4; jj++) {
                            unsigned int uu = *(const unsigned int*)&r_s[base + jj * 2];
                            s += lv[gg][jj * 2]     * bf2f(uu & 0xffffu);
                            s += lv[gg][jj * 2 + 1] * bf2f_hi(uu);
                        }
                        pk.us[gg] = f2bf(s * 0.125f);
                    }
                }
                *(uint2*)&o_s[(dl * 128 + w) * 68 + g0] = pk.u2;
            }
        }
        // ---- concat channels ----
#pragma unroll
        for (int dl = 0; dl < 4; dl++) {
            int d = d0 + dc + dl;
            union { u16 us[12]; uint2 u2[3]; } z;
            if (part == 0) {
#pragma unroll
                for (int k = 0; k < 12; k++) z.us[k] = (w >= d) ? lcv[k] : (u16)0;
                u16* dst = &o_s[(dl * 128 + w) * 68 + 40];
                *(uint2*)(dst + 0) = z.u2[0];
                *(uint2*)(dst + 4) = z.u2[1];
                *(uint2*)(dst + 8) = z.u2[2];
            } else {
                if (w >= d) {
                    int base = (w - d) * RS + 320;
#pragma unroll
                    for (int k = 0; k < 12; k++) z.us[k] = r_s[base + k];
                } else {
#pragma unroll
                    for (int k = 0; k < 12; k++) z.us[k] = 0;
                }
                u16* dst = &o_s[(dl * 128 + w) * 68 + 52];
                *(uint2*)(dst + 0) = z.u2[0];
                *(uint2*)(dst + 4) = z.u2[1];
                *(uint2*)(dst + 8) = z.u2[2];
            }
        }
        __syncthreads();
        // ---- flush 4 d-slabs, coalesced ----
#pragma unroll
        for (int i = 0; i < 16; i++) {
            int idx = i * 256 + tid;            // [0,4096)
            int dl  = idx >> 10;
            int rem = idx & 1023;
            int ww  = rem >> 3, cg = rem & 7;
            const u16* sp = &o_s[(dl * 128 + ww) * 68 + cg * 8];
            uint2 lo = *(const uint2*)sp;
            uint2 hi = *(const uint2*)(sp + 4);
            uint4 ov = { lo.x, lo.y, hi.x, hi.y };
            int d = d0 + dc + dl;
            *(uint4*)(vol + ((((size_t)bl * 48 + d) * 64 + h) * 128 + ww) * 64 + cg * 8) = ov;
        }
        __syncthreads();
    }
}

// ---------- conv1: implicit-GEMM MFMA with 2d x 2h output tile ----------
// block computes out slabs (d0..d0+1) x (h0..h0+1), each 128w x 32co.
// Per dd in [d0-1,d0+2]: stage 4 h-rows once (c-half at a time), feed all
// dependent taps of all 4 outputs -> staged bytes/output = 4 rows vs 9.
__global__ __launch_bounds__(256, 3) void conv1_mfma_kernel(
    const u16* __restrict__ vol, const u16* __restrict__ wf,
    const float* __restrict__ bias, u16* __restrict__ x1)
{
    __shared__ u16 a_s[4][5200];   // [row r][(wp*5+cg)*8], wp in [0,130), cg in [0,4)

    int bi = blockIdx.x;            // bl*768 + dt*32 + ht
    int ht = bi & 31;
    int dt = (bi >> 5) % 24;
    int bl = bi / 768;
    int h0 = ht * 2, d0 = dt * 2;
    int tid  = threadIdx.x;
    int lane = tid & 63, wid = tid >> 6;
    int lm = lane & 15, q = lane >> 4;

    f32x4 acc[2][2][2][2];          // [od][oh][mt][nt]
#pragma unroll
    for (int a = 0; a < 2; a++)
#pragma unroll
        for (int o = 0; o < 2; o++)
#pragma unroll
            for (int m = 0; m < 2; m++)
#pragma unroll
                for (int n = 0; n < 2; n++) acc[a][o][m][n] = { 0.f, 0.f, 0.f, 0.f };

#pragma unroll 1
    for (int dr = 0; dr < 4; dr++) {
        int dd = d0 - 1 + dr;
        if (dd < 0 || dd >= 48) continue;            // block-uniform
        const u16* srcbase = vol + ((size_t)bl * 48 + dd) * 64 * 8192;
        int od0v = (dr <= 2), od1v = (dr >= 1);

#pragma unroll 1
        for (int ch = 0; ch < 2; ch++) {
            __syncthreads();
            // ---- stage 4 rows, c-half ch ----
#pragma unroll
            for (int i = 0; i < 8; i++) {
                int idx = i * 256 + tid;             // [0,2048)
                int r = idx >> 9, rem = idx & 511;
                int w = rem >> 2, cg = rem & 3;
                int hh = h0 - 1 + r;
                uint4 v = { 0, 0, 0, 0 };
                if (hh >= 0 && hh < 64)
                    v = *(const uint4*)(srcbase + (size_t)hh * 8192 + w * 64 + ch * 32 + cg * 8);
                *(uint4*)&a_s[r][((w + 1) * 5 + cg) * 8] = v;
            }
            if (tid < 32) {                          // halo zeros wp=0,129
                uint4 z = { 0, 0, 0, 0 };
                int r = tid >> 3, side = (tid >> 2) & 1, cg = tid & 3;
                *(uint4*)&a_s[r][((side ? 129 : 0) * 5 + cg) * 8] = z;
            }
            __syncthreads();

#pragma unroll
            for (int r = 0; r < 4; r++) {
#pragma unroll
                for (int kw = 0; kw < 3; kw++) {
                    int kc = kw * 2 + ch;
                    bf16x8 afr[2];
#pragma unroll
                    for (int mt = 0; mt < 2; mt++)
                        afr[mt] = *(const bf16x8*)&a_s[r][((((wid * 2 + mt) * 16 + lm + kw) * 5) + q) * 8];
#pragma unroll
                    for (int od = 0; od < 2; od++) {
                        if (od == 0 ? !od0v : !od1v) continue;   // uniform
                        int kd = dr - od;
#pragma unroll
                        for (int oh = 0; oh < 2; oh++) {
                            if (oh == 0 ? (r > 2) : (r < 1)) continue;  // compile-time
                            int kh = r - oh;
                            int tap = kd * 3 + kh;
                            const u16* wp0 = wf + ((size_t)(tap * 2) * 6 + kc) * 512 + lane * 8;
                            bf16x8 b0 = *(const bf16x8*)wp0;
                            bf16x8 b1 = *(const bf16x8*)(wp0 + 6 * 512);
#pragma unroll
                            for (int mt = 0; mt < 2; mt++) {
                                acc[od][oh][mt][0] = __builtin_amdgcn_mfma_f32_16x16x32_bf16(afr[mt], b0, acc[od][oh][mt][0], 0, 0, 0);
                                acc[od][oh][mt][1] = __builtin_amdgcn_mfma_f32_16x16x32_bf16(afr[mt], b1, acc[od][oh][mt][1], 0, 0, 0);
                            }
                        }
                    }
                }
            }
        }
    }

    // ---- epilogue: 4 output slabs ----
#pragma unroll
    for (int od = 0; od < 2; od++)
#pragma unroll
        for (int oh = 0; oh < 2; oh++) {
            u16* xb = x1 + (((size_t)bl * 48 + d0 + od) * 64 + h0 + oh) * 4096;
#pragma unroll
            for (int mt = 0; mt < 2; mt++)
#pragma unroll
                for (int nt = 0; nt < 2; nt++) {
                    int co = nt * 16 + lm;
                    float bs = bias[co];
#pragma unroll
                    for (int rr = 0; rr < 4; rr++) {
                        int w = (wid * 2 + mt) * 16 + q * 4 + rr;
                        xb[w * 32 + co] = f2bf(fmaxf(acc[od][oh][mt][nt][rr] + bs, 0.f));
                    }
                }
        }
}

// ---------- conv2: implicit-GEMM MFMA with 2d x 2h output tile ----------
__global__ __launch_bounds__(256, 3) void conv2_mfma_kernel(
    const u16* __restrict__ x1, const u16* __restrict__ wf,
    const float* __restrict__ bias, float* __restrict__ out, int b0)
{
    __shared__ u16 a_s[4][5200];   // [row r][(wp*5+cg)*8], wp in [0,130), cg in [0,4)

    int bi = blockIdx.x;
    int ht = bi & 31;
    int dt = (bi >> 5) % 24;
    int bl = bi / 768;
    int h0 = ht * 2, d0 = dt * 2;
    int tid  = threadIdx.x;
    int lane = tid & 63, wid = tid >> 6;
    int lm = lane & 15, q = lane >> 4;

    f32x4 acc[2][2][2][2];
#pragma unroll
    for (int a = 0; a < 2; a++)
#pragma unroll
        for (int o = 0; o < 2; o++)
#pragma unroll
            for (int m = 0; m < 2; m++)
#pragma unroll
                for (int n = 0; n < 2; n++) acc[a][o][m][n] = { 0.f, 0.f, 0.f, 0.f };

#pragma unroll 1
    for (int dr = 0; dr < 4; dr++) {
        int dd = d0 - 1 + dr;
        if (dd < 0 || dd >= 48) continue;
        const u16* srcbase = x1 + ((size_t)bl * 48 + dd) * 64 * 4096;
        int od0v = (dr <= 2), od1v = (dr >= 1);

        __syncthreads();
#pragma unroll
        for (int i = 0; i < 8; i++) {
            int idx = i * 256 + tid;                 // [0,2048)
            int r = idx >> 9, rem = idx & 511;
            int w = rem >> 2, cg = rem & 3;
            int hh = h0 - 1 + r;
            uint4 v = { 0, 0, 0, 0 };
            if (hh >= 0 && hh < 64)
                v = *(const uint4*)(srcbase + (size_t)hh * 4096 + w * 32 + cg * 8);
            *(uint4*)&a_s[r][((w + 1) * 5 + cg) * 8] = v;
        }
        if (tid < 32) {
            uint4 z = { 0, 0, 0, 0 };
            int r = tid >> 3, side = (tid >> 2) & 1, cg = tid & 3;
            *(uint4*)&a_s[r][((side ? 129 : 0) * 5 + cg) * 8] = z;
        }
        __syncthreads();

#pragma unroll
        for (int r = 0; r < 4; r++) {
#pragma unroll
            for (int kw = 0; kw < 3; kw++) {
                bf16x8 afr[2];
#pragma unroll
                for (int mt = 0; mt < 2; mt++)
                    afr[mt] = *(const bf16x8*)&a_s[r][((((wid * 2 + mt) * 16 + lm + kw) * 5) + q) * 8];
#pragma unroll
                for (int od = 0; od < 2; od++) {
                    if (od == 0 ? !od0v : !od1v) continue;
                    int kd = dr - od;
#pragma unroll
                    for (int oh = 0; oh < 2; oh++) {
                        if (oh == 0 ? (r > 2) : (r < 1)) continue;
                        int kh = r - oh;
                        int tap = kd * 3 + kh;
                        const u16* wp0 = wf + ((size_t)(tap * 2) * 3 + kw) * 512 + lane * 8;
                        bf16x8 b0 = *(const bf16x8*)wp0;
                        bf16x8 b1 = *(const bf16x8*)(wp0 + 3 * 512);
#pragma unroll
                        for (int mt = 0; mt < 2; mt++) {
                            acc[od][oh][mt][0] = __builtin_amdgcn_mfma_f32_16x16x32_bf16(afr[mt], b0, acc[od][oh][mt][0], 0, 0, 0);
                            acc[od][oh][mt][1] = __builtin_amdgcn_mfma_f32_16x16x32_bf16(afr[mt], b1, acc[od][oh][mt][1], 0, 0, 0);
                        }
                    }
                }
            }
        }
    }

#pragma unroll
    for (int od = 0; od < 2; od++)
#pragma unroll
        for (int oh = 0; oh < 2; oh++)
#pragma unroll
            for (int mt = 0; mt < 2; mt++)
#pragma unroll
                for (int nt = 0; nt < 2; nt++) {
                    int co = nt * 16 + lm;
                    float bs = bias[co];
                    float4 o;
                    o.x = fmaxf(acc[od][oh][mt][nt][0] + bs, 0.f);
                    o.y = fmaxf(acc[od][oh][mt][nt][1] + bs, 0.f);
                    o.z = fmaxf(acc[od][oh][mt][nt][2] + bs, 0.f);
                    o.w = fmaxf(acc[od][oh][mt][nt][3] + bs, 0.f);
                    int wbase = (wid * 2 + mt) * 16 + q * 4;
                    *(float4*)(out + ((((size_t)(b0 + bl) * 32 + co) * 48 + d0 + od) * 64 + h0 + oh) * 128 + wbase) = o;
                }
}

extern "C" void kernel_launch(void* const* d_in, const int* in_sizes, int n_in,
                              void* d_out, int out_size, void* d_ws, size_t ws_size,
                              hipStream_t stream)
{
    const float* lg = (const float*)d_in[0];
    const float* rg = (const float*)d_in[1];
    const float* lc = (const float*)d_in[2];
    const float* rc = (const float*)d_in[3];
    const float* w1 = (const float*)d_in[4];
    const float* g1 = (const float*)d_in[5];
    const float* b1 = (const float*)d_in[6];
    const float* m1 = (const float*)d_in[7];
    const float* v1 = (const float*)d_in[8];
    const float* w2 = (const float*)d_in[9];
    const float* g2 = (const float*)d_in[10];
    const float* b2 = (const float*)d_in[11];
    const float* m2 = (const float*)d_in[12];
    const float* v2 = (const float*)d_in[13];
    (void)in_sizes; (void)n_in; (void)out_size; (void)ws_size;

    // ws layout (total ~50.5 MB, safely under observed ~96 MiB ws_size):
    char* ws = (char*)d_ws;
    u16*   wf1   = (u16*)ws;                 // 110,592 B
    u16*   wf2   = (u16*)(ws + 110592);      //  55,296 B
    float* bias1 = (float*)(ws + 165888);    //     128 B
    float* bias2 = (float*)(ws + 166016);    //     128 B
    u16*   x1    = (u16*)(ws + 166144);      // 50,331,648 B  [2][48][64][128][32] bf16

    wfrag_kernel<<<216, 256, 0, stream>>>(w1, g1, b1, m1, v1, wf1, bias1, 64, 6);
    wfrag_kernel<<<108, 256, 0, stream>>>(w2, g2, b2, m2, v2, wf2, bias2, 32, 3);

    // Per batch-pair: vol lives in the d_out region that this pair's conv2
    // output will overwrite (vol is dead by then; regions are byte-identical).
    for (int r = 0; r < 2; r++) {
        u16* vol = (u16*)d_out + (size_t)r * 50331648;   // [2][48][64][128][64] bf16
        vol_build_kernel<<<512, 256, 0, stream>>>(lg, rg, lc, rc, vol, 2 * r);
        conv1_mfma_kernel<<<1536, 256, 0, stream>>>(vol, wf1, bias1, x1);
        conv2_mfma_kernel<<<1536, 256, 0, stream>>>(x1, wf2, bias2, (float*)d_out, 2 * r);
    }
}